// Round 1
// baseline (695.318 us; speedup 1.0000x reference)
//
#include <hip/hip_runtime.h>

// segment_sum(h_t, batch, num_segments=10000)
//   h_t:   [N_NODES=1e6, FEAT=128] float32   (d_in[0])
//   batch: [N_NODES] int32, SORTED ascending (d_in[1])
//   out:   [10000, 128] float32              (d_out)
//
// batch is sorted => contiguous runs. Each wave (64 lanes) owns a contiguous
// chunk of ROWS_PER_WAVE rows; lane l accumulates cols [2l, 2l+1] in a float2
// register. Flush via atomicAdd only at run boundaries (~2.5 flushes/chunk),
// so atomic traffic is ~1.8M floats vs 512 MB of streaming reads.

#define FEAT 128
#define ROWS_PER_WAVE 256

__global__ __launch_bounds__(256) void segsum_kernel(
    const float* __restrict__ h,
    const int* __restrict__ batch,
    float* __restrict__ out,
    int n_rows) {
  const int wave = (blockIdx.x * blockDim.x + threadIdx.x) >> 6;
  const int lane = threadIdx.x & 63;

  long long row0 = (long long)wave * ROWS_PER_WAVE;
  if (row0 >= n_rows) return;
  long long row_end = row0 + ROWS_PER_WAVE;
  if (row_end > n_rows) row_end = n_rows;

  const int col = lane * 2;  // each lane handles 2 consecutive floats (8B)

  float2 acc;
  acc.x = 0.0f;
  acc.y = 0.0f;
  int cur = batch[row0];  // wave-uniform (broadcast load)

  for (long long r = row0; r < row_end; ++r) {
    const int b = batch[r];  // wave-uniform
    const float2 v = *(const float2*)(h + r * (long long)FEAT + col);
    if (b != cur) {  // wave-uniform branch: flush completed run
      float* dst = out + (long long)cur * FEAT + col;
      atomicAdd(dst + 0, acc.x);
      atomicAdd(dst + 1, acc.y);
      acc.x = 0.0f;
      acc.y = 0.0f;
      cur = b;
    }
    acc.x += v.x;
    acc.y += v.y;
  }
  // final flush (run may continue into next wave's chunk -> atomic)
  {
    float* dst = out + (long long)cur * FEAT + col;
    atomicAdd(dst + 0, acc.x);
    atomicAdd(dst + 1, acc.y);
  }
}

extern "C" void kernel_launch(void* const* d_in, const int* in_sizes, int n_in,
                              void* d_out, int out_size, void* d_ws, size_t ws_size,
                              hipStream_t stream) {
  const float* h_t = (const float*)d_in[0];
  const int* batch = (const int*)d_in[1];
  float* out = (float*)d_out;
  const int n_rows = in_sizes[1];  // N_NODES

  // d_out is poisoned with 0xAA before every launch — zero it first.
  hipMemsetAsync(d_out, 0, (size_t)out_size * sizeof(float), stream);

  const int n_waves = (n_rows + ROWS_PER_WAVE - 1) / ROWS_PER_WAVE;
  const int block = 256;                    // 4 waves/block
  const int waves_per_block = block / 64;
  const int grid = (n_waves + waves_per_block - 1) / waves_per_block;

  segsum_kernel<<<grid, block, 0, stream>>>(h_t, batch, out, n_rows);
}

// Round 2
// 638.088 us; speedup vs baseline: 1.0897x; 1.0897x over previous
//
#include <hip/hip_runtime.h>

// segment_sum(h_t, batch, num_segments=10000)
//   h_t:   [N_NODES=1e6, FEAT=128] float32   (d_in[0])
//   batch: [N_NODES] int32, SORTED ascending (d_in[1])
//   out:   [10000, 128] float32              (d_out)
//
// batch sorted => contiguous runs (avg ~100 rows). Wave owns ROWS_PER_WAVE
// contiguous rows; lane l accumulates cols [2l,2l+1] in registers; atomicAdd
// flush only at run boundaries (~10000 + n_chunks flushes total).
//
// R1 lesson: per-row `if (batch[r]!=cur)` with batch[r] from memory created a
// load->branch dependence every 512B row => latency-bound (~0.7 TB/s).
// Fix: unroll 8 rows, prefetch batch as int4 pairs and issue all 8 data loads
// BEFORE the (rare, wave-uniform) flush branches => 8-deep pipelining.

#define FEAT 128
#define ROWS_PER_WAVE 128   // 7813 waves -> ~7.6 blocks/CU of TLP

static __device__ inline float2 ntload2(const float* p) {
  unsigned long long raw =
      __builtin_nontemporal_load((const unsigned long long*)p);
  union { unsigned long long u; float2 f; } c;
  c.u = raw;
  return c.f;
}

__global__ __launch_bounds__(256) void segsum_kernel(
    const float* __restrict__ h,
    const int* __restrict__ batch,
    float* __restrict__ out,
    int n_rows) {
  const int wave = (blockIdx.x * blockDim.x + threadIdx.x) >> 6;
  const int lane = threadIdx.x & 63;

  long long row0 = (long long)wave * ROWS_PER_WAVE;
  if (row0 >= n_rows) return;
  long long row_end = row0 + ROWS_PER_WAVE;
  if (row_end > n_rows) row_end = n_rows;

  const int col = lane * 2;  // each lane: 2 consecutive floats (8B coalesced)

  float2 acc;
  acc.x = 0.0f;
  acc.y = 0.0f;
  int cur = batch[row0];  // wave-uniform broadcast load

  long long r = row0;

  // Main loop: 8 rows per iteration. All loads issued up front, then the
  // (wave-uniform, rarely-taken) boundary checks consume them in order.
  for (; r + 8 <= row_end; r += 8) {
    const int4 b0 = *(const int4*)(batch + r);
    const int4 b1 = *(const int4*)(batch + r + 4);
    const float* hp = h + r * (long long)FEAT + col;
    float2 v0 = ntload2(hp + 0 * FEAT);
    float2 v1 = ntload2(hp + 1 * FEAT);
    float2 v2 = ntload2(hp + 2 * FEAT);
    float2 v3 = ntload2(hp + 3 * FEAT);
    float2 v4 = ntload2(hp + 4 * FEAT);
    float2 v5 = ntload2(hp + 5 * FEAT);
    float2 v6 = ntload2(hp + 6 * FEAT);
    float2 v7 = ntload2(hp + 7 * FEAT);

#define STEP(B, V)                                      \
    if ((B) != cur) {                                   \
      float* dst = out + (long long)cur * FEAT + col;   \
      atomicAdd(dst + 0, acc.x);                        \
      atomicAdd(dst + 1, acc.y);                        \
      acc.x = 0.0f; acc.y = 0.0f;                       \
      cur = (B);                                        \
    }                                                   \
    acc.x += (V).x; acc.y += (V).y;

    STEP(b0.x, v0) STEP(b0.y, v1) STEP(b0.z, v2) STEP(b0.w, v3)
    STEP(b1.x, v4) STEP(b1.y, v5) STEP(b1.z, v6) STEP(b1.w, v7)
  }

  // Tail (n_rows not multiple of 8 within last chunk)
  for (; r < row_end; ++r) {
    const int b = batch[r];
    const float2 v = *(const float2*)(h + r * (long long)FEAT + col);
    STEP(b, v)
  }
#undef STEP

  // Final flush (run may continue into the next wave's chunk)
  {
    float* dst = out + (long long)cur * FEAT + col;
    atomicAdd(dst + 0, acc.x);
    atomicAdd(dst + 1, acc.y);
  }
}

extern "C" void kernel_launch(void* const* d_in, const int* in_sizes, int n_in,
                              void* d_out, int out_size, void* d_ws, size_t ws_size,
                              hipStream_t stream) {
  const float* h_t = (const float*)d_in[0];
  const int* batch = (const int*)d_in[1];
  float* out = (float*)d_out;
  const int n_rows = in_sizes[1];  // N_NODES

  // d_out is poisoned with 0xAA before every launch — zero it first.
  hipMemsetAsync(d_out, 0, (size_t)out_size * sizeof(float), stream);

  const int n_waves = (n_rows + ROWS_PER_WAVE - 1) / ROWS_PER_WAVE;
  const int block = 256;  // 4 waves/block
  const int waves_per_block = block / 64;
  const int grid = (n_waves + waves_per_block - 1) / waves_per_block;

  segsum_kernel<<<grid, block, 0, stream>>>(h_t, batch, out, n_rows);
}

// Round 3
// 636.415 us; speedup vs baseline: 1.0926x; 1.0026x over previous
//
#include <hip/hip_runtime.h>

// segment_sum(h_t, batch, num_segments=10000)
//   h_t:   [N_NODES=1e6, FEAT=128] float32   (d_in[0])
//   batch: [N_NODES] int32, SORTED ascending (d_in[1])
//   out:   [10000, 128] float32              (d_out)
//
// batch sorted => contiguous runs (avg ~100 rows). Wave owns ROWS_PER_WAVE
// contiguous rows. R3 layout: lane l handles cols [(l&31)*4 .. +3] of row
// r + (l>>5), so ONE global_load_dwordx4 per lane covers TWO full rows per
// wave (64 lanes x 16B = 1KB = 2 rows). 16-row unroll => 8 dwordx4 in flight
// (128 B/lane). Run boundaries handled per-lane (predicated flush, rare).
//
// R1 lesson: per-row load->branch dependence => latency-bound (~0.7 TB/s).
// R2 lesson: 8-deep dwordx2 pipeline => ~3.3 TB/s; still issue-bound at
// 8 B/lane loads. R3: 16 B/lane loads (coalescing sweet spot).

#define FEAT 128
#define ROWS_PER_WAVE 128  // 7813 waves -> ~7.6 blocks/CU

typedef float vfloat4 __attribute__((ext_vector_type(4)));

static __device__ inline vfloat4 ntload4(const float* p) {
  return __builtin_nontemporal_load((const vfloat4*)p);
}

__global__ __launch_bounds__(256) void segsum_kernel(
    const float* __restrict__ h,
    const int* __restrict__ batch,
    float* __restrict__ out,
    int n_rows) {
  const int wave = (blockIdx.x * blockDim.x + threadIdx.x) >> 6;
  const int lane = threadIdx.x & 63;
  const int sub = lane >> 5;         // which row of the pair this lane covers
  const int col = (lane & 31) * 4;   // 4 consecutive floats (16B coalesced)

  long long row0 = (long long)wave * ROWS_PER_WAVE;
  if (row0 >= n_rows) return;
  long long row_end = row0 + ROWS_PER_WAVE;
  if (row_end > n_rows) row_end = n_rows;

  vfloat4 acc = {0.0f, 0.0f, 0.0f, 0.0f};
  long long first = row0 + sub;
  int cur = batch[first < n_rows ? first : (n_rows - 1)];

#define STEP(B, V)                                        \
  {                                                       \
    const int b_ = (B);                                   \
    if (b_ != cur) { /* per-lane, rarely taken */         \
      float* dst = out + (long long)cur * FEAT + col;     \
      atomicAdd(dst + 0, acc.x);                          \
      atomicAdd(dst + 1, acc.y);                          \
      atomicAdd(dst + 2, acc.z);                          \
      atomicAdd(dst + 3, acc.w);                          \
      acc.x = 0.0f; acc.y = 0.0f;                         \
      acc.z = 0.0f; acc.w = 0.0f;                         \
      cur = b_;                                           \
    }                                                     \
    acc.x += (V).x; acc.y += (V).y;                       \
    acc.z += (V).z; acc.w += (V).w;                       \
  }

  long long r = row0;
  // Main loop: 16 rows (8 pairs) per iteration; all 12 loads issued before
  // any consume, giving 8 x dwordx4 (data) + 4 x dwordx4 (batch) in flight.
  for (; r + 16 <= row_end; r += 16) {
    const int4 ba = *(const int4*)(batch + r);
    const int4 bb = *(const int4*)(batch + r + 4);
    const int4 bc = *(const int4*)(batch + r + 8);
    const int4 bd = *(const int4*)(batch + r + 12);
    const float* hp = h + (r + sub) * (long long)FEAT + col;
    vfloat4 v0 = ntload4(hp + 0 * 2 * FEAT);
    vfloat4 v1 = ntload4(hp + 1 * 2 * FEAT);
    vfloat4 v2 = ntload4(hp + 2 * 2 * FEAT);
    vfloat4 v3 = ntload4(hp + 3 * 2 * FEAT);
    vfloat4 v4 = ntload4(hp + 4 * 2 * FEAT);
    vfloat4 v5 = ntload4(hp + 5 * 2 * FEAT);
    vfloat4 v6 = ntload4(hp + 6 * 2 * FEAT);
    vfloat4 v7 = ntload4(hp + 7 * 2 * FEAT);

    STEP(sub ? ba.y : ba.x, v0)
    STEP(sub ? ba.w : ba.z, v1)
    STEP(sub ? bb.y : bb.x, v2)
    STEP(sub ? bb.w : bb.z, v3)
    STEP(sub ? bc.y : bc.x, v4)
    STEP(sub ? bc.w : bc.z, v5)
    STEP(sub ? bd.y : bd.x, v6)
    STEP(sub ? bd.w : bd.z, v7)
  }

  // Pair tail
  for (; r + 2 <= row_end; r += 2) {
    const int b = batch[r + sub];
    const vfloat4 v = *(const vfloat4*)(h + (r + sub) * (long long)FEAT + col);
    STEP(b, v)
  }
  // Odd last row (only if n_rows is odd in the final chunk)
  if (r < row_end && sub == 0) {
    const int b = batch[r];
    const vfloat4 v = *(const vfloat4*)(h + r * (long long)FEAT + col);
    STEP(b, v)
  }
#undef STEP

  // Final flush (run may continue into the next wave's chunk)
  {
    float* dst = out + (long long)cur * FEAT + col;
    atomicAdd(dst + 0, acc.x);
    atomicAdd(dst + 1, acc.y);
    atomicAdd(dst + 2, acc.z);
    atomicAdd(dst + 3, acc.w);
  }
}

extern "C" void kernel_launch(void* const* d_in, const int* in_sizes, int n_in,
                              void* d_out, int out_size, void* d_ws, size_t ws_size,
                              hipStream_t stream) {
  const float* h_t = (const float*)d_in[0];
  const int* batch = (const int*)d_in[1];
  float* out = (float*)d_out;
  const int n_rows = in_sizes[1];  // N_NODES

  // d_out is poisoned with 0xAA before every launch — zero it first.
  hipMemsetAsync(d_out, 0, (size_t)out_size * sizeof(float), stream);

  const int n_waves = (n_rows + ROWS_PER_WAVE - 1) / ROWS_PER_WAVE;
  const int block = 256;  // 4 waves/block
  const int waves_per_block = block / 64;
  const int grid = (n_waves + waves_per_block - 1) / waves_per_block;

  segsum_kernel<<<grid, block, 0, stream>>>(h_t, batch, out, n_rows);
}